// Round 11
// baseline (63.063 us; speedup 1.0000x reference)
//
#include <hip/hip_runtime.h>
#include <math.h>

#define LSEQ 4096
#define NK 512
#define NB 16
#define NT 512          // threads per block (8 waves)
#define CK 8            // kernels per block
#define NCH (NK / CK)   // 64 chunks

// sx holds 4 shifted copies: sx[r*LSEQ + j] = x[j + r], r = 0..3
template <int KS>
__device__ __forceinline__ void rocket_body(
    const float* __restrict__ sx,
    const float* __restrict__ w, const float* __restrict__ bias,
    const int* __restrict__ off, const int* __restrict__ lout,
    int P, int li,
    float* smxc, int* scntc, int* sLoc)   // per-c LDS slots [8]
{
    const int tid = threadIdx.x;

    float wk[KS];
#pragma unroll
    for (int k = 0; k < KS; ++k) wk[k] = w[li * KS + k];
    const int o0  = off[li * KS + 0];
    const int o1  = off[li * KS + 1];
    const int d   = o1 - o0;          // dilation
    const int pad = P - o0;           // doubled pad
    const float bi = bias[li];
    const int   Lo = lout[li];

    // interior: all taps idx = t - pad + k*d in [0, LSEQ)
    int t_lo = min(pad, Lo);
    int t_hi = min(Lo, LSEQ - (KS - 1) * d + pad);
    if (t_hi < t_lo) t_hi = t_lo;
    int T0 = (t_lo + 3) & ~3;
    int T1 = t_hi & ~3;
    if (T1 < T0) { T0 = 0; T1 = 0; }   // degenerate: all via edge path

    float mx  = -INFINITY;
    int   cnt = 0;

    // ---- left edge [0, T0): scalar clamp + select-zero from copy 0 ----
    for (int t = tid; t < T0; t += NT) {
        float y = bi;
        int idx = t - pad;
#pragma unroll
        for (int k = 0; k < KS; ++k) {
            int ic = min(max(idx, 0), LSEQ - 1);
            float xv = sx[ic];
            xv = ((unsigned)idx < (unsigned)LSEQ) ? xv : 0.0f;
            y = fmaf(wk[k], xv, y);
            idx += d;
        }
        mx = fmaxf(mx, y); cnt += (y > 0.0f);
    }

    // ---- interior [T0, T1): one aligned ds_read_b128 per k, branch-free ----
    int ebk[KS];
#pragma unroll
    for (int k = 0; k < KS; ++k) {
        const int A0 = T0 - pad + k * d;   // block-uniform mod 4
        const int rk = A0 & 3;
        ebk[k] = rk * LSEQ + (k * d - pad - rk);   // sx + t + ebk[k] is 16B aligned
    }
    for (int t = T0 + 4 * tid; t < T1; t += 4 * NT) {
        float4 X[KS];
#pragma unroll
        for (int k = 0; k < KS; ++k) X[k] = *(const float4*)(sx + (t + ebk[k]));
        float y0 = bi, y1 = bi, y2 = bi, y3 = bi;
#pragma unroll
        for (int k = 0; k < KS; ++k) {
            y0 = fmaf(wk[k], X[k].x, y0);
            y1 = fmaf(wk[k], X[k].y, y1);
            y2 = fmaf(wk[k], X[k].z, y2);
            y3 = fmaf(wk[k], X[k].w, y3);
        }
        mx = fmaxf(mx, y0); cnt += (y0 > 0.0f);
        mx = fmaxf(mx, y1); cnt += (y1 > 0.0f);
        mx = fmaxf(mx, y2); cnt += (y2 > 0.0f);
        mx = fmaxf(mx, y3); cnt += (y3 > 0.0f);
    }

    // ---- right edge [T1, Lo): scalar clamp + select-zero from copy 0 ----
    for (int t = T1 + tid; t < Lo; t += NT) {
        float y = bi;
        int idx = t - pad;
#pragma unroll
        for (int k = 0; k < KS; ++k) {
            int ic = min(max(idx, 0), LSEQ - 1);
            float xv = sx[ic];
            xv = ((unsigned)idx < (unsigned)LSEQ) ? xv : 0.0f;
            y = fmaf(wk[k], xv, y);
            idx += d;
        }
        mx = fmaxf(mx, y); cnt += (y > 0.0f);
    }

    // ---- wave64 reduce, store to this kernel's private slots (no barrier) ----
#pragma unroll
    for (int o = 32; o > 0; o >>= 1) {
        mx = fmaxf(mx, __shfl_down(mx, o, 64));
        cnt += __shfl_down(cnt, o, 64);
    }
    const int wid = tid >> 6;
    if ((tid & 63) == 0) { smxc[wid] = mx; scntc[wid] = cnt; }
    if (tid == 0) *sLoc = Lo;
}

__global__ __launch_bounds__(NT, 2) void rocket_v11_kernel(
    const float* __restrict__ x, const int* __restrict__ perm,
    const int* __restrict__ Pp,
    const float* __restrict__ w0, const float* __restrict__ b0,
    const int* __restrict__ off0, const int* __restrict__ l0,
    const float* __restrict__ w1, const float* __restrict__ b1,
    const int* __restrict__ off1, const int* __restrict__ l1,
    const float* __restrict__ w2, const float* __restrict__ b2,
    const int* __restrict__ off2, const int* __restrict__ l2,
    int n0, int n01,
    float* __restrict__ out)
{
    __shared__ float sx[4 * LSEQ];   // 64 KB: 4 shifted copies
    __shared__ int   sj[CK];
    __shared__ int   sLo[CK];
    __shared__ float smx[CK][8];
    __shared__ int   scnt[CK][8];

    const int chunk = blockIdx.x;
    const int b     = blockIdx.y;
    const int tid   = threadIdx.x;

    // inverse permutation for this block's CK kernels (NT == NK)
    const int p0 = perm[tid];
#pragma unroll
    for (int c = 0; c < CK; ++c) {
        if (p0 == chunk + NCH * c) sj[c] = tid;
    }

    // stage 4 shifted copies; all stores are contiguous b128 (conflict-free)
    const float* xg = x + (size_t)b * LSEQ;
    const float4* x4 = (const float4*)xg;
    for (int m = tid; m < LSEQ / 4; m += NT) {
        const float4 v = x4[m];
        const float4 n = x4[min(m + 1, LSEQ / 4 - 1)];  // tail slots never read
        const int e = 4 * m;
        *(float4*)(sx + e)            = v;
        *(float4*)(sx + LSEQ + e)     = make_float4(v.y, v.z, v.w, n.x);
        *(float4*)(sx + 2 * LSEQ + e) = make_float4(v.z, v.w, n.x, n.y);
        *(float4*)(sx + 3 * LSEQ + e) = make_float4(v.w, n.x, n.y, n.z);
    }
    __syncthreads();

    const int P = *Pp;

    // barrier-free kernel loop: each c writes private LDS slots
#pragma unroll 1
    for (int c = 0; c < CK; ++c) {
        const int gid = chunk + NCH * c;
        if (gid < n0) {
            rocket_body<7>(sx, w0, b0, off0, l0, P, gid, smx[c], scnt[c], &sLo[c]);
        } else if (gid < n01) {
            rocket_body<9>(sx, w1, b1, off1, l1, P, gid - n0, smx[c], scnt[c], &sLo[c]);
        } else {
            rocket_body<11>(sx, w2, b2, off2, l2, P, gid - n01, smx[c], scnt[c], &sLo[c]);
        }
    }
    __syncthreads();

    // finalize: thread c writes kernel c's two outputs
    if (tid < CK) {
        const int c = tid;
        float m = smx[c][0];
        int   cn = scnt[c][0];
#pragma unroll
        for (int i = 1; i < 8; ++i) { m = fmaxf(m, smx[c][i]); cn += scnt[c][i]; }
        const int outj = sj[c];
        const int Lo   = sLo[c];
        out[b * (2 * NK) + 2 * outj]     = m;
        out[b * (2 * NK) + 2 * outj + 1] = (float)cn / (float)Lo;
    }
}

extern "C" void kernel_launch(void* const* d_in, const int* in_sizes, int n_in,
                              void* d_out, int out_size, void* d_ws, size_t ws_size,
                              hipStream_t stream) {
    const float* x    = (const float*)d_in[0];
    const int*   perm = (const int*)d_in[1];
    const int*   Pp   = (const int*)d_in[2];
    const float* w0   = (const float*)d_in[3];
    const float* b0   = (const float*)d_in[4];
    const int*   off0 = (const int*)d_in[5];
    const int*   l0   = (const int*)d_in[6];
    const float* w1   = (const float*)d_in[7];
    const float* b1   = (const float*)d_in[8];
    const int*   off1 = (const int*)d_in[9];
    const int*   l1   = (const int*)d_in[10];
    const float* w2   = (const float*)d_in[11];
    const float* b2   = (const float*)d_in[12];
    const int*   off2 = (const int*)d_in[13];
    const int*   l2   = (const int*)d_in[14];

    const int n0 = in_sizes[4];
    const int n1 = in_sizes[8];

    float* out = (float*)d_out;

    rocket_v11_kernel<<<dim3(NCH, NB), NT, 0, stream>>>(
        x, perm, Pp, w0, b0, off0, l0, w1, b1, off1, l1, w2, b2, off2, l2,
        n0, n0 + n1, out);
}

// Round 12
// 59.853 us; speedup vs baseline: 1.0536x; 1.0536x over previous
//
#include <hip/hip_runtime.h>
#include <math.h>

#define LSEQ 4096
#define NK 512
#define NB 16
#define NT 1024         // threads per block (16 waves)
#define CK 16           // kernels per block
#define NCH (NK / CK)   // 32 chunks -> grid 512 blocks (2/CU, single round)

typedef float v2f __attribute__((ext_vector_type(2)));

// sx holds 4 shifted copies: sx[r*LSEQ + j] = x[j + r], r = 0..3
template <int KS>
__device__ __forceinline__ void rocket_body(
    const float* __restrict__ sx,
    const float* __restrict__ w, const float* __restrict__ bias,
    const int* __restrict__ off, const int* __restrict__ lout,
    int P, int li,
    float* smxc, int* scntc, int* sLoc)   // per-c LDS slots [16]
{
    const int tid = threadIdx.x;

    float wk[KS];
#pragma unroll
    for (int k = 0; k < KS; ++k) wk[k] = w[li * KS + k];
    const int o0  = off[li * KS + 0];
    const int o1  = off[li * KS + 1];
    const int d   = o1 - o0;          // dilation
    const int pad = P - o0;           // doubled pad
    const float bi = bias[li];
    const int   Lo = lout[li];

    // interior: all taps idx = t - pad + k*d in [0, LSEQ)
    int t_lo = min(pad, Lo);
    int t_hi = min(Lo, LSEQ - (KS - 1) * d + pad);
    if (t_hi < t_lo) t_hi = t_lo;
    int T0 = (t_lo + 3) & ~3;
    int T1 = t_hi & ~3;
    if (T1 < T0) { T0 = 0; T1 = 0; }   // degenerate: all via edge path

    float mx  = -INFINITY;
    int   cnt = 0;

    // ---- left edge [0, T0): scalar clamp + select-zero from copy 0 ----
    for (int t = tid; t < T0; t += NT) {
        float y = bi;
        int idx = t - pad;
#pragma unroll
        for (int k = 0; k < KS; ++k) {
            int ic = min(max(idx, 0), LSEQ - 1);
            float xv = sx[ic];
            xv = ((unsigned)idx < (unsigned)LSEQ) ? xv : 0.0f;
            y = fmaf(wk[k], xv, y);
            idx += d;
        }
        mx = fmaxf(mx, y); cnt += (y > 0.0f);
    }

    // ---- interior [T0, T1): one aligned ds_read_b128 per k, packed fma ----
    int ebk[KS];
#pragma unroll
    for (int k = 0; k < KS; ++k) {
        const int A0 = T0 - pad + k * d;   // block-uniform mod 4
        const int rk = A0 & 3;
        ebk[k] = rk * LSEQ + (k * d - pad - rk);   // sx + t + ebk[k] is 16B aligned
    }
    v2f mx2 = { -INFINITY, -INFINITY };
    for (int t = T0 + 4 * tid; t < T1; t += 4 * NT) {
        float4 X[KS];
#pragma unroll
        for (int k = 0; k < KS; ++k) X[k] = *(const float4*)(sx + (t + ebk[k]));
        v2f y01 = { bi, bi }, y23 = { bi, bi };
#pragma unroll
        for (int k = 0; k < KS; ++k) {
            const v2f wv = { wk[k], wk[k] };
            const v2f xlo = { X[k].x, X[k].y };
            const v2f xhi = { X[k].z, X[k].w };
            y01 = __builtin_elementwise_fma(wv, xlo, y01);
            y23 = __builtin_elementwise_fma(wv, xhi, y23);
        }
        mx2 = __builtin_elementwise_max(mx2, __builtin_elementwise_max(y01, y23));
        cnt += (y01.x > 0.0f);
        cnt += (y01.y > 0.0f);
        cnt += (y23.x > 0.0f);
        cnt += (y23.y > 0.0f);
    }
    mx = fmaxf(mx, fmaxf(mx2.x, mx2.y));

    // ---- right edge [T1, Lo): scalar clamp + select-zero from copy 0 ----
    for (int t = T1 + tid; t < Lo; t += NT) {
        float y = bi;
        int idx = t - pad;
#pragma unroll
        for (int k = 0; k < KS; ++k) {
            int ic = min(max(idx, 0), LSEQ - 1);
            float xv = sx[ic];
            xv = ((unsigned)idx < (unsigned)LSEQ) ? xv : 0.0f;
            y = fmaf(wk[k], xv, y);
            idx += d;
        }
        mx = fmaxf(mx, y); cnt += (y > 0.0f);
    }

    // ---- wave64 reduce, store to this kernel's private slots (no barrier) ----
#pragma unroll
    for (int o = 32; o > 0; o >>= 1) {
        mx = fmaxf(mx, __shfl_down(mx, o, 64));
        cnt += __shfl_down(cnt, o, 64);
    }
    const int wid = tid >> 6;
    if ((tid & 63) == 0) { smxc[wid] = mx; scntc[wid] = cnt; }
    if (tid == 0) *sLoc = Lo;
}

__global__ __launch_bounds__(NT, 8) void rocket_v12_kernel(
    const float* __restrict__ x, const int* __restrict__ perm,
    const int* __restrict__ Pp,
    const float* __restrict__ w0, const float* __restrict__ b0,
    const int* __restrict__ off0, const int* __restrict__ l0,
    const float* __restrict__ w1, const float* __restrict__ b1,
    const int* __restrict__ off1, const int* __restrict__ l1,
    const float* __restrict__ w2, const float* __restrict__ b2,
    const int* __restrict__ off2, const int* __restrict__ l2,
    int n0, int n01,
    float* __restrict__ out)
{
    __shared__ float sx[4 * LSEQ];   // 64 KB: 4 shifted copies
    __shared__ int   sj[CK];
    __shared__ int   sLo[CK];
    __shared__ float smx[CK][16];
    __shared__ int   scnt[CK][16];

    const int chunk = blockIdx.x;
    const int b     = blockIdx.y;
    const int tid   = threadIdx.x;

    // inverse permutation for this block's CK kernels
    if (tid < NK) {
        const int p0 = perm[tid];
#pragma unroll
        for (int c = 0; c < CK; ++c) {
            if (p0 == chunk + NCH * c) sj[c] = tid;
        }
    }

    // stage 4 shifted copies; all stores are contiguous b128 (conflict-free)
    const float* xg = x + (size_t)b * LSEQ;
    const float4* x4 = (const float4*)xg;
    {
        const int m = tid;                               // LSEQ/4 == NT
        const float4 v = x4[m];
        const float4 n = x4[min(m + 1, LSEQ / 4 - 1)];   // tail slots never read
        const int e = 4 * m;
        *(float4*)(sx + e)            = v;
        *(float4*)(sx + LSEQ + e)     = make_float4(v.y, v.z, v.w, n.x);
        *(float4*)(sx + 2 * LSEQ + e) = make_float4(v.z, v.w, n.x, n.y);
        *(float4*)(sx + 3 * LSEQ + e) = make_float4(v.w, n.x, n.y, n.z);
    }
    __syncthreads();

    const int P = *Pp;

    // barrier-free kernel loop: each c writes private LDS slots
#pragma unroll 1
    for (int c = 0; c < CK; ++c) {
        const int gid = chunk + NCH * c;
        if (gid < n0) {
            rocket_body<7>(sx, w0, b0, off0, l0, P, gid, smx[c], scnt[c], &sLo[c]);
        } else if (gid < n01) {
            rocket_body<9>(sx, w1, b1, off1, l1, P, gid - n0, smx[c], scnt[c], &sLo[c]);
        } else {
            rocket_body<11>(sx, w2, b2, off2, l2, P, gid - n01, smx[c], scnt[c], &sLo[c]);
        }
    }
    __syncthreads();

    // finalize: thread c writes kernel c's two outputs
    if (tid < CK) {
        const int c = tid;
        float m = smx[c][0];
        int   cn = scnt[c][0];
#pragma unroll
        for (int i = 1; i < 16; ++i) { m = fmaxf(m, smx[c][i]); cn += scnt[c][i]; }
        const int outj = sj[c];
        const int Lo   = sLo[c];
        out[b * (2 * NK) + 2 * outj]     = m;
        out[b * (2 * NK) + 2 * outj + 1] = (float)cn / (float)Lo;
    }
}

extern "C" void kernel_launch(void* const* d_in, const int* in_sizes, int n_in,
                              void* d_out, int out_size, void* d_ws, size_t ws_size,
                              hipStream_t stream) {
    const float* x    = (const float*)d_in[0];
    const int*   perm = (const int*)d_in[1];
    const int*   Pp   = (const int*)d_in[2];
    const float* w0   = (const float*)d_in[3];
    const float* b0   = (const float*)d_in[4];
    const int*   off0 = (const int*)d_in[5];
    const int*   l0   = (const int*)d_in[6];
    const float* w1   = (const float*)d_in[7];
    const float* b1   = (const float*)d_in[8];
    const int*   off1 = (const int*)d_in[9];
    const int*   l1   = (const int*)d_in[10];
    const float* w2   = (const float*)d_in[11];
    const float* b2   = (const float*)d_in[12];
    const int*   off2 = (const int*)d_in[13];
    const int*   l2   = (const int*)d_in[14];

    const int n0 = in_sizes[4];
    const int n1 = in_sizes[8];

    float* out = (float*)d_out;

    rocket_v12_kernel<<<dim3(NCH, NB), NT, 0, stream>>>(
        x, perm, Pp, w0, b0, off0, l0, w1, b1, off1, l1, w2, b2, off2, l2,
        n0, n0 + n1, out);
}

// Round 13
// 59.192 us; speedup vs baseline: 1.0654x; 1.0112x over previous
//
#include <hip/hip_runtime.h>
#include <math.h>

#define LSEQ 4096
#define NK 512
#define NB 16
#define NT 1024         // threads per block (16 waves)
#define CK 16           // kernels per block
#define NCH (NK / CK)   // 32 chunks -> grid 512 blocks (2/CU, single round)

typedef float v2f __attribute__((ext_vector_type(2)));

// sx holds 4 shifted copies: sx[r*LSEQ + j] = x[j + r], r = 0..3
template <int KS>
__device__ __forceinline__ void rocket_body(
    const float* __restrict__ sx,
    const float* __restrict__ w, const float* __restrict__ bias,
    const int* __restrict__ off, const int* __restrict__ lout,
    int P, int li,
    float* smxc, int* scntc, int* sLoc)   // per-c LDS slots [16]
{
    const int tid = threadIdx.x;

    float wk[KS];
#pragma unroll
    for (int k = 0; k < KS; ++k) wk[k] = w[li * KS + k];
    const int o0  = off[li * KS + 0];
    const int o1  = off[li * KS + 1];
    const int d   = o1 - o0;          // dilation
    const int pad = P - o0;           // doubled pad
    const float bi = bias[li];
    const int   Lo = lout[li];

    // interior: all taps idx = t - pad + k*d in [0, LSEQ)
    int t_lo = min(pad, Lo);
    int t_hi = min(Lo, LSEQ - (KS - 1) * d + pad);
    if (t_hi < t_lo) t_hi = t_lo;
    int T0 = (t_lo + 3) & ~3;
    int T1 = t_hi & ~3;
    if (T1 < T0) { T0 = 0; T1 = 0; }   // degenerate: all via edge path

    float mx  = -INFINITY;
    int   cnt = 0;

    // ---- left edge [0, T0): scalar clamp + select-zero from copy 0 ----
    for (int t = tid; t < T0; t += NT) {
        float y = bi;
        int idx = t - pad;
#pragma unroll
        for (int k = 0; k < KS; ++k) {
            int ic = min(max(idx, 0), LSEQ - 1);
            float xv = sx[ic];
            xv = ((unsigned)idx < (unsigned)LSEQ) ? xv : 0.0f;
            y = fmaf(wk[k], xv, y);
            idx += d;
        }
        mx = fmaxf(mx, y); cnt += (y > 0.0f);
    }

    // ---- interior [T0, T1): aligned ds_read_b128, k chunked by 4 (VGPR cap) ----
    int ebk[KS];
#pragma unroll
    for (int k = 0; k < KS; ++k) {
        const int A0 = T0 - pad + k * d;   // block-uniform mod 4
        const int rk = A0 & 3;
        ebk[k] = rk * LSEQ + (k * d - pad - rk);   // sx + t + ebk[k] is 16B aligned
    }
    v2f mx2 = { -INFINITY, -INFINITY };
    for (int t = T0 + 4 * tid; t < T1; t += 4 * NT) {
        v2f y01 = { bi, bi }, y23 = { bi, bi };
#pragma unroll
        for (int kb = 0; kb < KS; kb += 4) {
            const int ke = (kb + 4 < KS) ? (kb + 4) : KS;
            float4 Xc[4];
#pragma unroll
            for (int k = kb; k < ke; ++k)
                Xc[k - kb] = *(const float4*)(sx + (t + ebk[k]));
#pragma unroll
            for (int k = kb; k < ke; ++k) {
                const v2f wv  = { wk[k], wk[k] };
                const v2f xlo = { Xc[k - kb].x, Xc[k - kb].y };
                const v2f xhi = { Xc[k - kb].z, Xc[k - kb].w };
                y01 = __builtin_elementwise_fma(wv, xlo, y01);
                y23 = __builtin_elementwise_fma(wv, xhi, y23);
            }
        }
        mx2 = __builtin_elementwise_max(mx2, __builtin_elementwise_max(y01, y23));
        cnt += (y01.x > 0.0f);
        cnt += (y01.y > 0.0f);
        cnt += (y23.x > 0.0f);
        cnt += (y23.y > 0.0f);
    }
    mx = fmaxf(mx, fmaxf(mx2.x, mx2.y));

    // ---- right edge [T1, Lo): scalar clamp + select-zero from copy 0 ----
    for (int t = T1 + tid; t < Lo; t += NT) {
        float y = bi;
        int idx = t - pad;
#pragma unroll
        for (int k = 0; k < KS; ++k) {
            int ic = min(max(idx, 0), LSEQ - 1);
            float xv = sx[ic];
            xv = ((unsigned)idx < (unsigned)LSEQ) ? xv : 0.0f;
            y = fmaf(wk[k], xv, y);
            idx += d;
        }
        mx = fmaxf(mx, y); cnt += (y > 0.0f);
    }

    // ---- wave64 reduce, store to this kernel's private slots (no barrier) ----
#pragma unroll
    for (int o = 32; o > 0; o >>= 1) {
        mx = fmaxf(mx, __shfl_down(mx, o, 64));
        cnt += __shfl_down(cnt, o, 64);
    }
    const int wid = tid >> 6;
    if ((tid & 63) == 0) { smxc[wid] = mx; scntc[wid] = cnt; }
    if (tid == 0) *sLoc = Lo;
}

__global__ __launch_bounds__(NT, 8) void rocket_v13_kernel(
    const float* __restrict__ x, const int* __restrict__ perm,
    const int* __restrict__ Pp,
    const float* __restrict__ w0, const float* __restrict__ b0,
    const int* __restrict__ off0, const int* __restrict__ l0,
    const float* __restrict__ w1, const float* __restrict__ b1,
    const int* __restrict__ off1, const int* __restrict__ l1,
    const float* __restrict__ w2, const float* __restrict__ b2,
    const int* __restrict__ off2, const int* __restrict__ l2,
    int n0, int n01,
    float* __restrict__ out)
{
    __shared__ float sx[4 * LSEQ];   // 64 KB: 4 shifted copies
    __shared__ int   sj[CK];
    __shared__ int   sLo[CK];
    __shared__ float smx[CK][16];
    __shared__ int   scnt[CK][16];

    const int chunk = blockIdx.x;
    const int b     = blockIdx.y;
    const int tid   = threadIdx.x;

    // inverse permutation for this block's CK kernels
    if (tid < NK) {
        const int p0 = perm[tid];
#pragma unroll
        for (int c = 0; c < CK; ++c) {
            if (p0 == chunk + NCH * c) sj[c] = tid;
        }
    }

    // stage 4 shifted copies; all stores are contiguous b128 (conflict-free)
    const float* xg = x + (size_t)b * LSEQ;
    const float4* x4 = (const float4*)xg;
    {
        const int m = tid;                               // LSEQ/4 == NT
        const float4 v = x4[m];
        const float4 n = x4[min(m + 1, LSEQ / 4 - 1)];   // tail slots never read
        const int e = 4 * m;
        *(float4*)(sx + e)            = v;
        *(float4*)(sx + LSEQ + e)     = make_float4(v.y, v.z, v.w, n.x);
        *(float4*)(sx + 2 * LSEQ + e) = make_float4(v.z, v.w, n.x, n.y);
        *(float4*)(sx + 3 * LSEQ + e) = make_float4(v.w, n.x, n.y, n.z);
    }
    __syncthreads();

    const int P = *Pp;

    // barrier-free kernel loop: each c writes private LDS slots
#pragma unroll 1
    for (int c = 0; c < CK; ++c) {
        const int gid = chunk + NCH * c;
        if (gid < n0) {
            rocket_body<7>(sx, w0, b0, off0, l0, P, gid, smx[c], scnt[c], &sLo[c]);
        } else if (gid < n01) {
            rocket_body<9>(sx, w1, b1, off1, l1, P, gid - n0, smx[c], scnt[c], &sLo[c]);
        } else {
            rocket_body<11>(sx, w2, b2, off2, l2, P, gid - n01, smx[c], scnt[c], &sLo[c]);
        }
    }
    __syncthreads();

    // finalize: thread c writes kernel c's two outputs
    if (tid < CK) {
        const int c = tid;
        float m = smx[c][0];
        int   cn = scnt[c][0];
#pragma unroll
        for (int i = 1; i < 16; ++i) { m = fmaxf(m, smx[c][i]); cn += scnt[c][i]; }
        const int outj = sj[c];
        const int Lo   = sLo[c];
        out[b * (2 * NK) + 2 * outj]     = m;
        out[b * (2 * NK) + 2 * outj + 1] = (float)cn / (float)Lo;
    }
}

extern "C" void kernel_launch(void* const* d_in, const int* in_sizes, int n_in,
                              void* d_out, int out_size, void* d_ws, size_t ws_size,
                              hipStream_t stream) {
    const float* x    = (const float*)d_in[0];
    const int*   perm = (const int*)d_in[1];
    const int*   Pp   = (const int*)d_in[2];
    const float* w0   = (const float*)d_in[3];
    const float* b0   = (const float*)d_in[4];
    const int*   off0 = (const int*)d_in[5];
    const int*   l0   = (const int*)d_in[6];
    const float* w1   = (const float*)d_in[7];
    const float* b1   = (const float*)d_in[8];
    const int*   off1 = (const int*)d_in[9];
    const int*   l1   = (const int*)d_in[10];
    const float* w2   = (const float*)d_in[11];
    const float* b2   = (const float*)d_in[12];
    const int*   off2 = (const int*)d_in[13];
    const int*   l2   = (const int*)d_in[14];

    const int n0 = in_sizes[4];
    const int n1 = in_sizes[8];

    float* out = (float*)d_out;

    rocket_v13_kernel<<<dim3(NCH, NB), NT, 0, stream>>>(
        x, perm, Pp, w0, b0, off0, l0, w1, b1, off1, l1, w2, b2, off2, l2,
        n0, n0 + n1, out);
}